// Round 7
// baseline (157.201 us; speedup 1.0000x reference)
//
#include <hip/hip_runtime.h>
#include <hip/hip_bf16.h>

typedef float    f32x4  __attribute__((ext_vector_type(4)));
typedef short    bf16x8 __attribute__((ext_vector_type(8)));
typedef unsigned u32x2  __attribute__((ext_vector_type(2)));

#define Bsz  8192
#define Dsz  64
#define Hsz  128
#define Tsz  41
#define ROWS 16
#define NT   128

#define MFMA(a,b,c) __builtin_amdgcn_mfma_f32_16x16x32_bf16((a),(b),(c),0,0,0)

__device__ __forceinline__ float fast_tanh(float x) {
    float ax = __builtin_fabsf(x);
    float e  = __expf(-2.0f * ax);
    float r  = (1.0f - e) * __builtin_amdgcn_rcpf(1.0f + e);
    return __builtin_copysignf(r, x);
}

// packed RNE bf16 pair convert: dst = bf16(a) | bf16(b)<<16
__device__ __forceinline__ unsigned cvt_pk_bf16(float a, float b) {
    unsigned r;
    asm("v_cvt_pk_bf16_f32 %0, %1, %2" : "=v"(r) : "v"(a), "v"(b));
    return r;
}

// split f32x4 -> packed H (2 dwords) and packed L, L = bf16(x - f32(H))
__device__ __forceinline__ void splitq(const f32x4& x, u32x2& H, u32x2& L) {
    H[0] = cvt_pk_bf16(x[0], x[1]);
    H[1] = cvt_pk_bf16(x[2], x[3]);
    float h0 = __uint_as_float(H[0] << 16);
    float h1 = __uint_as_float(H[0] & 0xFFFF0000u);
    float h2 = __uint_as_float(H[1] << 16);
    float h3 = __uint_as_float(H[1] & 0xFFFF0000u);
    L[0] = cvt_pk_bf16(x[0] - h0, x[1] - h1);
    L[1] = cvt_pk_bf16(x[2] - h2, x[3] - h3);
}

__device__ __forceinline__ unsigned short bf2u(__hip_bfloat16 h) {
    union { __hip_bfloat16 b; unsigned short u; } v; v.b = h; return v.u;
}

union FragU { bf16x8 f; unsigned short h[8]; };

// weight split (init only, cold path)
__device__ __forceinline__ void split8(const float* x, bf16x8& hi, bf16x8& lo) {
    FragU H, L;
    #pragma unroll
    for (int i = 0; i < 8; ++i) {
        __hip_bfloat16 hb = __float2bfloat16(x[i]);
        H.h[i] = bf2u(hb);
        L.h[i] = bf2u(__float2bfloat16(x[i] - __bfloat162float(hb)));
    }
    hi = H.f; lo = L.f;
}

__device__ __forceinline__ bf16x8 ldb128(const unsigned short* base, int byteoff) {
    return *(const bf16x8*)((const char*)base + byteoff);
}
__device__ __forceinline__ void stb64(unsigned short* base, int byteoff, u32x2 v) {
    *(u32x2*)((char*)base + byteoff) = v;
}

__global__ __launch_bounds__(NT, 1)
void ode_mfma7(const float* __restrict__ z0, const float* __restrict__ t,
               const float* __restrict__ W1, const float* __restrict__ b1,
               const float* __restrict__ W2, const float* __restrict__ b2,
               float* __restrict__ out)
{
    // bf16 H/L tiles, [batch_row][feature], byte-index XOR-swizzled by (row&7)<<4
    __shared__ __align__(16) unsigned short zHs[ROWS * Dsz], zLs[ROWS * Dsz];
    __shared__ __align__(16) unsigned short aHs[ROWS * Hsz], aLs[ROWS * Hsz];
    __shared__ float ts[Tsz];

    const int tid  = threadIdx.x;
    const int lane = tid & 63;
    const int w    = tid >> 6;   // wave 0/1: layer1 h-cols [64w,64w+64), layer2 d [32w,32w+32)
    const int g    = lane >> 4;
    const int c    = lane & 15;  // batch row within tile
    const int r0   = blockIdx.x * ROWS;

    if (tid < Tsz) ts[tid] = t[tid];

    // ---- z master in registers: zreg[ml] = z[batch=c][d = 32w+16ml+4g .. +3] ----
    f32x4 zreg[2];
    zreg[0] = *(const f32x4*)&z0[(r0 + c) * Dsz + 32*w + 4*g];
    zreg[1] = *(const f32x4*)&z0[(r0 + c) * Dsz + 32*w + 16 + 4*g];

    // ---- W1^T A-frags: lane holds W1T[h=16(4w+j)+c][d=32kt+8g+i] ----
    bf16x8 w1tH[4][2], w1tL[4][2];   // [j][kt]
    #pragma unroll
    for (int j = 0; j < 4; ++j) {
        const int n = 16*(4*w + j) + c;
        #pragma unroll
        for (int kt = 0; kt < 2; ++kt) {
            float tmp[8];
            #pragma unroll
            for (int i = 0; i < 8; ++i) tmp[i] = W1[(32*kt + 8*g + i) * Hsz + n];
            split8(tmp, w1tH[j][kt], w1tL[j][kt]);
        }
    }
    // ---- W2^T A-frags: lane holds W2T[d=32w+16ml+c][h=32kt2+8g+i] ----
    bf16x8 w2tH[2][4], w2tL[2][4];   // [ml][kt2]
    #pragma unroll
    for (int ml = 0; ml < 2; ++ml) {
        const int n = 32*w + 16*ml + c;
        #pragma unroll
        for (int kt2 = 0; kt2 < 4; ++kt2) {
            float tmp[8];
            #pragma unroll
            for (int i = 0; i < 8; ++i) tmp[i] = W2[(32*kt2 + 8*g + i) * Dsz + n];
            split8(tmp, w2tH[ml][kt2], w2tL[ml][kt2]);
        }
    }
    f32x4 b1v[4], b2v[2];
    #pragma unroll
    for (int j = 0; j < 4; ++j)
        #pragma unroll
        for (int reg = 0; reg < 4; ++reg) b1v[j][reg] = b1[16*(4*w + j) + 4*g + reg];
    #pragma unroll
    for (int ml = 0; ml < 2; ++ml)
        #pragma unroll
        for (int reg = 0; reg < 4; ++reg) b2v[ml][reg] = b2[32*w + 16*ml + 4*g + reg];

    // ---- loop-invariant swizzled LDS byte offsets ----
    int zwr[2], awr[4], zrd[2], ard[4];
    #pragma unroll
    for (int ml = 0; ml < 2; ++ml)
        zwr[ml] = (c*128 + (32*w + 16*ml + 4*g)*2) ^ ((c & 7) << 4);     // b64 write
    #pragma unroll
    for (int j = 0; j < 4; ++j)
        awr[j] = (c*256 + (16*(4*w + j) + 4*g)*2) ^ ((c & 7) << 4);      // b64 write
    #pragma unroll
    for (int kt = 0; kt < 2; ++kt)
        zrd[kt] = (c*128 + (32*kt + 8*g)*2) ^ ((c & 7) << 4);            // b128 read
    #pragma unroll
    for (int kt2 = 0; kt2 < 4; ++kt2)
        ard[kt2] = (c*256 + (32*kt2 + 8*g)*2) ^ ((c & 7) << 4);          // b128 read

    auto z_to_lds = [&]() {
        #pragma unroll
        for (int ml = 0; ml < 2; ++ml) {
            u32x2 H, L;
            splitq(zreg[ml], H, L);
            stb64(zHs, zwr[ml], H);
            stb64(zLs, zwr[ml], L);
        }
    };

    z_to_lds();
    __syncthreads();

    const int n_steps = (int)ceilf(fabsf(ts[1] - ts[0]) / 0.05f);   // = 2 (exact in f32)

    for (int iv = 0; iv < Tsz - 1; ++iv) {
        const float h = (ts[iv + 1] - ts[iv]) / (float)n_steps;
        for (int s = 0; s < n_steps; ++s) {
            // ---- layer 1 (transposed): a^T = tanh(W1^T @ z^T + b1), 4 nt per wave ----
            bf16x8 zh0 = ldb128(zHs, zrd[0]), zh1 = ldb128(zHs, zrd[1]);
            bf16x8 zl0 = ldb128(zLs, zrd[0]), zl1 = ldb128(zLs, zrd[1]);
            #pragma unroll
            for (int j = 0; j < 4; ++j) {
                f32x4 aA = b1v[j];
                f32x4 aB = {0,0,0,0}, aC = {0,0,0,0};
                aA = MFMA(w1tH[j][0], zh0, aA);
                aB = MFMA(w1tH[j][0], zl0, aB);
                aC = MFMA(w1tL[j][0], zh0, aC);
                aA = MFMA(w1tH[j][1], zh1, aA);
                aB = MFMA(w1tH[j][1], zl1, aB);
                aC = MFMA(w1tL[j][1], zh1, aC);
                f32x4 av = (aA + aB) + aC;
                f32x4 tv;
                #pragma unroll
                for (int reg = 0; reg < 4; ++reg) tv[reg] = fast_tanh(av[reg]);
                u32x2 H, L;
                splitq(tv, H, L);
                stb64(aHs, awr[j], H);
                stb64(aLs, awr[j], L);
            }
            __syncthreads();
            // ---- layer 2 (transposed): dz^T = W2^T @ a^T + b2, 2 mt per wave ----
            bf16x8 ah0 = ldb128(aHs, ard[0]), ah1 = ldb128(aHs, ard[1]);
            bf16x8 ah2 = ldb128(aHs, ard[2]), ah3 = ldb128(aHs, ard[3]);
            bf16x8 al0 = ldb128(aLs, ard[0]), al1 = ldb128(aLs, ard[1]);
            bf16x8 al2 = ldb128(aLs, ard[2]), al3 = ldb128(aLs, ard[3]);
            #pragma unroll
            for (int ml = 0; ml < 2; ++ml) {
                f32x4 dA = b2v[ml];
                f32x4 dB = {0,0,0,0}, dC = {0,0,0,0};
                dA = MFMA(w2tH[ml][0], ah0, dA);
                dB = MFMA(w2tH[ml][0], al0, dB);
                dC = MFMA(w2tL[ml][0], ah0, dC);
                dA = MFMA(w2tH[ml][1], ah1, dA);
                dB = MFMA(w2tH[ml][1], al1, dB);
                dC = MFMA(w2tL[ml][1], ah1, dC);
                dA = MFMA(w2tH[ml][2], ah2, dA);
                dB = MFMA(w2tH[ml][2], al2, dB);
                dC = MFMA(w2tL[ml][2], ah2, dC);
                dA = MFMA(w2tH[ml][3], ah3, dA);
                dB = MFMA(w2tH[ml][3], al3, dB);
                dC = MFMA(w2tL[ml][3], ah3, dC);
                f32x4 dz = (dA + dB) + dC;
                zreg[ml] += h * dz;
            }
            z_to_lds();
            __syncthreads();
        }
    }

    // ---- write result ----
    *(f32x4*)&out[(r0 + c) * Dsz + 32*w + 4*g]      = zreg[0];
    *(f32x4*)&out[(r0 + c) * Dsz + 32*w + 16 + 4*g] = zreg[1];
}

extern "C" void kernel_launch(void* const* d_in, const int* in_sizes, int n_in,
                              void* d_out, int out_size, void* d_ws, size_t ws_size,
                              hipStream_t stream) {
    const float* z0 = (const float*)d_in[0];
    const float* t  = (const float*)d_in[1];
    const float* W1 = (const float*)d_in[2];
    const float* b1 = (const float*)d_in[3];
    const float* W2 = (const float*)d_in[4];
    const float* b2 = (const float*)d_in[5];
    float* out = (float*)d_out;
    (void)in_sizes; (void)n_in; (void)out_size; (void)d_ws; (void)ws_size;

    ode_mfma7<<<dim3(Bsz / ROWS), dim3(NT), 0, stream>>>(z0, t, W1, b1, W2, b2, out);
}

// Round 8
// 92.685 us; speedup vs baseline: 1.6961x; 1.6961x over previous
//
#include <hip/hip_runtime.h>
#include <hip/hip_bf16.h>

typedef float    f32x4  __attribute__((ext_vector_type(4)));
typedef short    bf16x8 __attribute__((ext_vector_type(8)));
typedef unsigned u32x2  __attribute__((ext_vector_type(2)));

#define Bsz  8192
#define Dsz  64
#define Hsz  128
#define Tsz  41
#define ROWS 16
#define NT   256

#define MFMA(a,b,c) __builtin_amdgcn_mfma_f32_16x16x32_bf16((a),(b),(c),0,0,0)

__device__ __forceinline__ float fast_tanh(float x) {
    float ax = __builtin_fabsf(x);
    float e  = __expf(-2.0f * ax);
    float r  = (1.0f - e) * __builtin_amdgcn_rcpf(1.0f + e);
    return __builtin_copysignf(r, x);
}

// RNE bf16 in HIGH 16 bits (no NaN guard: inputs provably finite/bounded)
__device__ __forceinline__ unsigned rne_u(float x) {
    unsigned u = __float_as_uint(x);
    return u + 0x7FFFu + ((u >> 16) & 1u);
}

// lean split: H = RNE bf16 pair (packed), L = RTZ bf16 pair of residual.
// v_perm grabs the high16 of two dwords -> one dword, no shifts needed.
__device__ __forceinline__ void splitq(const f32x4& x, u32x2& H, u32x2& L) {
    unsigned r0 = rne_u(x[0]), r1 = rne_u(x[1]);
    unsigned r2 = rne_u(x[2]), r3 = rne_u(x[3]);
    H[0] = __builtin_amdgcn_perm(r1, r0, 0x07060302u);   // bf16(x0) | bf16(x1)<<16
    H[1] = __builtin_amdgcn_perm(r3, r2, 0x07060302u);
    float l0 = x[0] - __uint_as_float(r0 & 0xFFFF0000u);
    float l1 = x[1] - __uint_as_float(r1 & 0xFFFF0000u);
    float l2 = x[2] - __uint_as_float(r2 & 0xFFFF0000u);
    float l3 = x[3] - __uint_as_float(r3 & 0xFFFF0000u);
    L[0] = __builtin_amdgcn_perm(__float_as_uint(l1), __float_as_uint(l0), 0x07060302u);
    L[1] = __builtin_amdgcn_perm(__float_as_uint(l3), __float_as_uint(l2), 0x07060302u);
}

__device__ __forceinline__ unsigned short bf2u(__hip_bfloat16 h) {
    union { __hip_bfloat16 b; unsigned short u; } v; v.b = h; return v.u;
}

union FragU { bf16x8 f; unsigned short h[8]; };

// weight split (init only, cold path — keep the safe library casts)
__device__ __forceinline__ void split8(const float* x, bf16x8& hi, bf16x8& lo) {
    FragU H, L;
    #pragma unroll
    for (int i = 0; i < 8; ++i) {
        __hip_bfloat16 hb = __float2bfloat16(x[i]);
        H.h[i] = bf2u(hb);
        L.h[i] = bf2u(__float2bfloat16(x[i] - __bfloat162float(hb)));
    }
    hi = H.f; lo = L.f;
}

__device__ __forceinline__ bf16x8 ldb128(const unsigned short* base, int byteoff) {
    return *(const bf16x8*)((const char*)base + byteoff);
}
__device__ __forceinline__ void stb64(unsigned short* base, int byteoff, u32x2 v) {
    *(u32x2*)((char*)base + byteoff) = v;
}

__global__ __launch_bounds__(NT, 2)
void ode_mfma8(const float* __restrict__ z0, const float* __restrict__ t,
               const float* __restrict__ W1, const float* __restrict__ b1,
               const float* __restrict__ W2, const float* __restrict__ b2,
               float* __restrict__ out)
{
    // bf16 H/L tiles, [batch_row][feature], byte-index XOR-swizzled by (row&7)<<4
    __shared__ __align__(16) unsigned short zHs[ROWS * Dsz], zLs[ROWS * Dsz];
    __shared__ __align__(16) unsigned short aHs[ROWS * Hsz], aLs[ROWS * Hsz];
    __shared__ float ts[Tsz];

    const int tid  = threadIdx.x;
    const int lane = tid & 63;
    const int w    = tid >> 6;   // wave: layer1 h-cols 32w..+31, layer2 d-cols 16w..+15
    const int g    = lane >> 4;
    const int c    = lane & 15;  // batch row within tile
    const int r0   = blockIdx.x * ROWS;

    if (tid < Tsz) ts[tid] = t[tid];

    // ---- z master in registers: zreg[reg] = z[batch=c][d = 16w + 4g + reg] ----
    f32x4 zreg = *(const f32x4*)&z0[(r0 + c) * Dsz + 16*w + 4*g];

    // ---- W1^T A-fragments: lane holds W1T[h=16(2w+nt)+c][d=32kt+8g+i] ----
    bf16x8 w1tH[2][2], w1tL[2][2];   // [nt][kt]
    #pragma unroll
    for (int nt = 0; nt < 2; ++nt) {
        const int n = 32*w + 16*nt + c;
        #pragma unroll
        for (int kt = 0; kt < 2; ++kt) {
            float tmp[8];
            #pragma unroll
            for (int i = 0; i < 8; ++i) tmp[i] = W1[(32*kt + 8*g + i) * Hsz + n];
            split8(tmp, w1tH[nt][kt], w1tL[nt][kt]);
        }
    }
    // ---- W2^T A-fragments: lane holds W2T[d=16w+c][h=32kt2+8g+i] ----
    bf16x8 w2tH[4], w2tL[4];         // [kt2]
    {
        const int n = 16*w + c;
        #pragma unroll
        for (int kt2 = 0; kt2 < 4; ++kt2) {
            float tmp[8];
            #pragma unroll
            for (int i = 0; i < 8; ++i) tmp[i] = W2[(32*kt2 + 8*g + i) * Dsz + n];
            split8(tmp, w2tH[kt2], w2tL[kt2]);
        }
    }
    f32x4 b1v[2], b2v;
    #pragma unroll
    for (int nt = 0; nt < 2; ++nt)
        #pragma unroll
        for (int reg = 0; reg < 4; ++reg)
            b1v[nt][reg] = b1[16*(2*w + nt) + 4*g + reg];
    #pragma unroll
    for (int reg = 0; reg < 4; ++reg) b2v[reg] = b2[16*w + 4*g + reg];

    // ---- loop-invariant swizzled LDS byte offsets ----
    const int zw = (c*128 + (16*w + 4*g)*2) ^ ((c & 7) << 4);          // b64 write
    int zrd[2], aw[2], ard[4];
    #pragma unroll
    for (int kt = 0; kt < 2; ++kt)
        zrd[kt] = (c*128 + (32*kt + 8*g)*2) ^ ((c & 7) << 4);          // b128 read
    #pragma unroll
    for (int nt = 0; nt < 2; ++nt)
        aw[nt] = (c*256 + (32*w + 16*nt + 4*g)*2) ^ ((c & 7) << 4);    // b64 write
    #pragma unroll
    for (int kt2 = 0; kt2 < 4; ++kt2)
        ard[kt2] = (c*256 + (32*kt2 + 8*g)*2) ^ ((c & 7) << 4);        // b128 read

    auto z_to_lds = [&]() {
        u32x2 H, L;
        splitq(zreg, H, L);
        stb64(zHs, zw, H);
        stb64(zLs, zw, L);
    };

    z_to_lds();
    __syncthreads();

    const int n_steps = (int)ceilf(fabsf(ts[1] - ts[0]) / 0.05f);   // = 2 (exact in f32)

    for (int iv = 0; iv < Tsz - 1; ++iv) {
        const float h = (ts[iv + 1] - ts[iv]) / (float)n_steps;
        for (int s = 0; s < n_steps; ++s) {
            // ---- layer 1 (transposed): a^T = tanh(W1^T @ z^T + b1) ----
            bf16x8 zh0 = ldb128(zHs, zrd[0]), zh1 = ldb128(zHs, zrd[1]);
            bf16x8 zl0 = ldb128(zLs, zrd[0]), zl1 = ldb128(zLs, zrd[1]);
            #pragma unroll
            for (int nt = 0; nt < 2; ++nt) {
                f32x4 aA = b1v[nt];
                f32x4 aB = {0,0,0,0}, aC = {0,0,0,0};
                __builtin_amdgcn_s_setprio(1);
                aA = MFMA(w1tH[nt][0], zh0, aA);
                aB = MFMA(w1tH[nt][0], zl0, aB);
                aC = MFMA(w1tL[nt][0], zh0, aC);
                aA = MFMA(w1tH[nt][1], zh1, aA);
                aB = MFMA(w1tH[nt][1], zl1, aB);
                aC = MFMA(w1tL[nt][1], zh1, aC);
                __builtin_amdgcn_s_setprio(0);
                f32x4 av = (aA + aB) + aC;
                f32x4 tv;
                #pragma unroll
                for (int reg = 0; reg < 4; ++reg) tv[reg] = fast_tanh(av[reg]);
                u32x2 H, L;
                splitq(tv, H, L);
                stb64(aHs, aw[nt], H);
                stb64(aLs, aw[nt], L);
            }
            __syncthreads();
            // ---- layer 2 (transposed): dz^T = W2^T @ a^T + b2 ----
            bf16x8 ah0 = ldb128(aHs, ard[0]), ah1 = ldb128(aHs, ard[1]);
            bf16x8 ah2 = ldb128(aHs, ard[2]), ah3 = ldb128(aHs, ard[3]);
            bf16x8 al0 = ldb128(aLs, ard[0]), al1 = ldb128(aLs, ard[1]);
            bf16x8 al2 = ldb128(aLs, ard[2]), al3 = ldb128(aLs, ard[3]);
            f32x4 dA = b2v;
            f32x4 dB = {0,0,0,0}, dC = {0,0,0,0};
            __builtin_amdgcn_s_setprio(1);
            dA = MFMA(w2tH[0], ah0, dA);
            dB = MFMA(w2tH[0], al0, dB);
            dC = MFMA(w2tL[0], ah0, dC);
            dA = MFMA(w2tH[1], ah1, dA);
            dB = MFMA(w2tH[1], al1, dB);
            dC = MFMA(w2tL[1], ah1, dC);
            dA = MFMA(w2tH[2], ah2, dA);
            dB = MFMA(w2tH[2], al2, dB);
            dC = MFMA(w2tL[2], ah2, dC);
            dA = MFMA(w2tH[3], ah3, dA);
            dB = MFMA(w2tH[3], al3, dB);
            dC = MFMA(w2tL[3], ah3, dC);
            __builtin_amdgcn_s_setprio(0);
            f32x4 dz = (dA + dB) + dC;
            zreg += h * dz;
            z_to_lds();                  // 2 b64 writes
            __syncthreads();
        }
    }

    // ---- write result (one dwordx4 per lane) ----
    *(f32x4*)&out[(r0 + c) * Dsz + 16*w + 4*g] = zreg;
}

extern "C" void kernel_launch(void* const* d_in, const int* in_sizes, int n_in,
                              void* d_out, int out_size, void* d_ws, size_t ws_size,
                              hipStream_t stream) {
    const float* z0 = (const float*)d_in[0];
    const float* t  = (const float*)d_in[1];
    const float* W1 = (const float*)d_in[2];
    const float* b1 = (const float*)d_in[3];
    const float* W2 = (const float*)d_in[4];
    const float* b2 = (const float*)d_in[5];
    float* out = (float*)d_out;
    (void)in_sizes; (void)n_in; (void)out_size; (void)d_ws; (void)ws_size;

    ode_mfma8<<<dim3(Bsz / ROWS), dim3(NT), 0, stream>>>(z0, t, W1, b1, W2, b2, out);
}